// Round 6
// baseline (38.980 us; speedup 1.0000x reference)
//
#include <hip/hip_runtime.h>

// feature_map: (B=16, H=27, W=48, C=512) fp32
// nmses:       (B=16, R=100, 4) fp32  (cx, cy, w, h in pixels)
// output:      (B, R, 7, 7, C) fp32
#define BB   16
#define RR   100
#define HH   27
#define WW   48
#define CC   512
#define PP   7

#define C4       (CC / 4)            // 128 float4 per pixel
#define ROW4     (WW * C4)           // 6144 float4 per (b,y)
#define IMG4     (HH * ROW4)         // 165888 float4 per b

#define TOTAL4   (BB * RR * PP * PP * C4)   // 10,035,200 float4
#define NTHREADS (TOTAL4 / 4)               // 4 float4 per thread
#define NBLOCKS  (NTHREADS / 256)           // 9800; 9800 % 8 == 0
#define NXCD     8

typedef float vf4 __attribute__((ext_vector_type(4)));

// Per-cell sampling state (all wave-uniform / scalar).
struct CellS {
    const vf4* rT;
    const vf4* rB;
    int xo0, xo1;        // x0*C4, x1i*C4
    float lx, ly;
    bool valid;
};

__device__ __forceinline__ CellS cell_setup(const float* __restrict__ fm,
                                            const float* __restrict__ nms,
                                            int cell)
{
    CellS s;
    const int px = cell % PP;
    int t        = cell / PP;
    const int py = t % PP;
    t           /= PP;

    const int ts = __builtin_amdgcn_readfirstlane(t);
    const int b  = ts / RR;

    const vf4 box = ((const vf4*)nms)[ts];
    const float cx = box.x, cy = box.y, w = box.z, h = box.w;

    const float x1 = (cx - w * 0.5f) / 768.0f;
    const float x2 = (cx + w * 0.5f) / 768.0f;
    const float y1 = (cy - h * 0.5f) / 432.0f;
    const float y2 = (cy + h * 0.5f) / 432.0f;

    const float ys = y1 * 26.0f + (float)py * (y2 - y1) * 26.0f / 6.0f;
    const float xs = x1 * 47.0f + (float)px * (x2 - x1) * 47.0f / 6.0f;

    s.valid = (ys >= 0.0f) && (ys <= 26.0f) &&
              (xs >= 0.0f) && (xs <= 47.0f);

    const float y0f = floorf(ys);
    const float x0f = floorf(xs);
    s.ly = ys - y0f;
    s.lx = xs - x0f;

    int y0 = (int)y0f; y0 = min(max(y0, 0), HH - 1);
    const int y1i = min(y0 + 1, HH - 1);
    int x0 = (int)x0f; x0 = min(max(x0, 0), WW - 1);
    const int x1i = min(x0 + 1, WW - 1);

    const vf4* img = ((const vf4*)fm) + (size_t)b * IMG4;
    s.rT  = img + y0  * ROW4;
    s.rB  = img + y1i * ROW4;
    s.xo0 = x0  * C4;
    s.xo1 = x1i * C4;
    return s;
}

__global__ __launch_bounds__(256) void roi_crop_resize_kernel(
    const float* __restrict__ fm,
    const float* __restrict__ nms,
    float* __restrict__ out)
{
    // XCD-aware bijective swizzle (NBLOCKS % 8 == 0): contiguous box ranges
    // per XCD keep each XCD's ~2.65MB image slice in its private 4MB L2.
    const int bid  = blockIdx.x;
    const int wgid = (bid % NXCD) * (NBLOCKS / NXCD) + bid / NXCD;

    const int idx   = wgid * 256 + threadIdx.x;  // [0, NTHREADS)
    const int c4    = idx & 63;                  // lane's float4 slot
    const int pair  = idx >> 6;                  // wave handles 2 cells
    const int cell0 = pair * 2;
    const int cell1 = cell0 + 1;

    const CellS s0 = cell_setup(fm, nms, cell0);
    const CellS s1 = cell_setup(fm, nms, cell1);

    // Issue all 16 independent 16B loads before any use (deep MLP).
    vf4 a_tl0, a_tr0, a_bl0, a_br0, a_tl1, a_tr1, a_bl1, a_br1;
    vf4 b_tl0, b_tr0, b_bl0, b_br0, b_tl1, b_tr1, b_bl1, b_br1;

    if (s0.valid) {
        a_tl0 = s0.rT[s0.xo0 + c4];      a_tr0 = s0.rT[s0.xo1 + c4];
        a_bl0 = s0.rB[s0.xo0 + c4];      a_br0 = s0.rB[s0.xo1 + c4];
        a_tl1 = s0.rT[s0.xo0 + c4 + 64]; a_tr1 = s0.rT[s0.xo1 + c4 + 64];
        a_bl1 = s0.rB[s0.xo0 + c4 + 64]; a_br1 = s0.rB[s0.xo1 + c4 + 64];
    }
    if (s1.valid) {
        b_tl0 = s1.rT[s1.xo0 + c4];      b_tr0 = s1.rT[s1.xo1 + c4];
        b_bl0 = s1.rB[s1.xo0 + c4];      b_br0 = s1.rB[s1.xo1 + c4];
        b_tl1 = s1.rT[s1.xo0 + c4 + 64]; b_tr1 = s1.rT[s1.xo1 + c4 + 64];
        b_bl1 = s1.rB[s1.xo0 + c4 + 64]; b_br1 = s1.rB[s1.xo1 + c4 + 64];
    }

    vf4 o00, o01, o10, o11;
    if (s0.valid) {
        const vf4 top0 = a_tl0 + (a_tr0 - a_tl0) * s0.lx;
        const vf4 bot0 = a_bl0 + (a_br0 - a_bl0) * s0.lx;
        o00 = top0 + (bot0 - top0) * s0.ly;
        const vf4 top1 = a_tl1 + (a_tr1 - a_tl1) * s0.lx;
        const vf4 bot1 = a_bl1 + (a_br1 - a_bl1) * s0.lx;
        o01 = top1 + (bot1 - top1) * s0.ly;
    } else {
        o00 = (vf4)(0.0f); o01 = (vf4)(0.0f);
    }
    if (s1.valid) {
        const vf4 top0 = b_tl0 + (b_tr0 - b_tl0) * s1.lx;
        const vf4 bot0 = b_bl0 + (b_br0 - b_bl0) * s1.lx;
        o10 = top0 + (bot0 - top0) * s1.ly;
        const vf4 top1 = b_tl1 + (b_tr1 - b_tl1) * s1.lx;
        const vf4 bot1 = b_bl1 + (b_br1 - b_bl1) * s1.lx;
        o11 = top1 + (bot1 - top1) * s1.ly;
    } else {
        o10 = (vf4)(0.0f); o11 = (vf4)(0.0f);
    }

    // A/B vs R5: PLAIN stores (write-back through L2) instead of nontemporal.
    // Tests whether NT's forced-early-eviction was serializing against the
    // L2 read stream.
    vf4* op = ((vf4*)out) + (size_t)cell0 * C4 + c4;
    op[0]   = o00;
    op[64]  = o01;
    op[128] = o10;
    op[192] = o11;
}

extern "C" void kernel_launch(void* const* d_in, const int* in_sizes, int n_in,
                              void* d_out, int out_size, void* d_ws, size_t ws_size,
                              hipStream_t stream)
{
    const float* fm  = (const float*)d_in[0];
    const float* nms = (const float*)d_in[1];
    float* out = (float*)d_out;

    roi_crop_resize_kernel<<<NBLOCKS, 256, 0, stream>>>(fm, nms, out);
}

// Round 7
// 38.073 us; speedup vs baseline: 1.0238x; 1.0238x over previous
//
#include <hip/hip_runtime.h>

// feature_map: (B=16, H=27, W=48, C=512) fp32
// nmses:       (B=16, R=100, 4) fp32  (cx, cy, w, h in pixels)
// output:      (B, R, 7, 7, C) fp32
#define BB   16
#define RR   100
#define HH   27
#define WW   48
#define CC   512
#define PP   7

#define C4       (CC / 4)            // 128 float4 per pixel
#define ROW4     (WW * C4)           // 6144 float4 per (b,y)
#define IMG4     (HH * ROW4)         // 165888 float4 per b

#define TOTAL4   (BB * RR * PP * PP * C4)   // 10,035,200 float4
#define NTHREADS (TOTAL4 / 4)               // 4 float4 per thread
#define NBLOCKS  (NTHREADS / 256)           // 9800; 9800 % 8 == 0
#define NXCD     8

typedef float vf4 __attribute__((ext_vector_type(4)));

// Per-cell sampling state (all wave-uniform / scalar).
struct CellS {
    const vf4* rT;
    const vf4* rB;
    int xo0, xo1;        // x0*C4, x1i*C4
    float lx, ly;
    bool valid;
};

__device__ __forceinline__ CellS cell_setup(const float* __restrict__ fm,
                                            const float* __restrict__ nms,
                                            int cell)
{
    CellS s;
    const int px = cell % PP;
    int t        = cell / PP;
    const int py = t % PP;
    t           /= PP;

    const int ts = __builtin_amdgcn_readfirstlane(t);
    const int b  = ts / RR;

    const vf4 box = ((const vf4*)nms)[ts];
    const float cx = box.x, cy = box.y, w = box.z, h = box.w;

    const float x1 = (cx - w * 0.5f) / 768.0f;
    const float x2 = (cx + w * 0.5f) / 768.0f;
    const float y1 = (cy - h * 0.5f) / 432.0f;
    const float y2 = (cy + h * 0.5f) / 432.0f;

    const float ys = y1 * 26.0f + (float)py * (y2 - y1) * 26.0f / 6.0f;
    const float xs = x1 * 47.0f + (float)px * (x2 - x1) * 47.0f / 6.0f;

    s.valid = (ys >= 0.0f) && (ys <= 26.0f) &&
              (xs >= 0.0f) && (xs <= 47.0f);

    const float y0f = floorf(ys);
    const float x0f = floorf(xs);
    s.ly = ys - y0f;
    s.lx = xs - x0f;

    int y0 = (int)y0f; y0 = min(max(y0, 0), HH - 1);
    const int y1i = min(y0 + 1, HH - 1);
    int x0 = (int)x0f; x0 = min(max(x0, 0), WW - 1);
    const int x1i = min(x0 + 1, WW - 1);

    const vf4* img = ((const vf4*)fm) + (size_t)b * IMG4;
    s.rT  = img + y0  * ROW4;
    s.rB  = img + y1i * ROW4;
    s.xo0 = x0  * C4;
    s.xo1 = x1i * C4;
    return s;
}

__global__ __launch_bounds__(256) void roi_crop_resize_kernel(
    const float* __restrict__ fm,
    const float* __restrict__ nms,
    float* __restrict__ out)
{
    // XCD-aware bijective swizzle (NBLOCKS % 8 == 0).
    const int bid  = blockIdx.x;
    const int wgid = (bid % NXCD) * (NBLOCKS / NXCD) + bid / NXCD;

    const int idx   = wgid * 256 + threadIdx.x;  // [0, NTHREADS)
    const int c4    = idx & 63;                  // lane's float4 slot
    const int pair  = idx >> 6;                  // wave handles 2 cells
    const int cell0 = pair * 2;
    const int cell1 = cell0 + 1;

    const CellS s0 = cell_setup(fm, nms, cell0);
    const CellS s1 = cell_setup(fm, nms, cell1);

    // Wave-uniform corner-sharing detection: cells are px-adjacent, so when
    // floor(xs) doesn't advance, cell1's corner addresses duplicate cell0's.
    // Eliminating the duplicate LOAD INSTRUCTIONS cuts VMEM-port bytes (an
    // L1 hit still costs full port occupancy; a register copy is free).
    const bool rows_same = s0.valid & s1.valid &
                           (s0.rT == s1.rT) & (s0.rB == s1.rB);
    const bool share_all = rows_same & (s1.xo0 == s0.xo0) & (s1.xo1 == s0.xo1);
    const bool share_col = rows_same & (!share_all) & (s1.xo0 == s0.xo1);

    vf4 a_tl0, a_tr0, a_bl0, a_br0, a_tl1, a_tr1, a_bl1, a_br1;
    vf4 b_tl0, b_tr0, b_bl0, b_br0, b_tl1, b_tr1, b_bl1, b_br1;

    if (s0.valid) {
        a_tl0 = s0.rT[s0.xo0 + c4];      a_tr0 = s0.rT[s0.xo1 + c4];
        a_bl0 = s0.rB[s0.xo0 + c4];      a_br0 = s0.rB[s0.xo1 + c4];
        a_tl1 = s0.rT[s0.xo0 + c4 + 64]; a_tr1 = s0.rT[s0.xo1 + c4 + 64];
        a_bl1 = s0.rB[s0.xo0 + c4 + 64]; a_br1 = s0.rB[s0.xo1 + c4 + 64];
    }
    if (s1.valid) {
        if (share_all) {
            // Identical 4 corner pixels: pure register reuse, 8 loads saved.
            b_tl0 = a_tl0; b_tr0 = a_tr0; b_bl0 = a_bl0; b_br0 = a_br0;
            b_tl1 = a_tl1; b_tr1 = a_tr1; b_bl1 = a_bl1; b_br1 = a_br1;
        } else if (share_col) {
            // cell1's left column == cell0's right column: 4 loads saved.
            b_tl0 = a_tr0; b_bl0 = a_br0;
            b_tl1 = a_tr1; b_bl1 = a_br1;
            b_tr0 = s1.rT[s1.xo1 + c4];      b_br0 = s1.rB[s1.xo1 + c4];
            b_tr1 = s1.rT[s1.xo1 + c4 + 64]; b_br1 = s1.rB[s1.xo1 + c4 + 64];
        } else {
            b_tl0 = s1.rT[s1.xo0 + c4];      b_tr0 = s1.rT[s1.xo1 + c4];
            b_bl0 = s1.rB[s1.xo0 + c4];      b_br0 = s1.rB[s1.xo1 + c4];
            b_tl1 = s1.rT[s1.xo0 + c4 + 64]; b_tr1 = s1.rT[s1.xo1 + c4 + 64];
            b_bl1 = s1.rB[s1.xo0 + c4 + 64]; b_br1 = s1.rB[s1.xo1 + c4 + 64];
        }
    }

    vf4 o00, o01, o10, o11;
    if (s0.valid) {
        const vf4 top0 = a_tl0 + (a_tr0 - a_tl0) * s0.lx;
        const vf4 bot0 = a_bl0 + (a_br0 - a_bl0) * s0.lx;
        o00 = top0 + (bot0 - top0) * s0.ly;
        const vf4 top1 = a_tl1 + (a_tr1 - a_tl1) * s0.lx;
        const vf4 bot1 = a_bl1 + (a_br1 - a_bl1) * s0.lx;
        o01 = top1 + (bot1 - top1) * s0.ly;
    } else {
        o00 = (vf4)(0.0f); o01 = (vf4)(0.0f);
    }
    if (s1.valid) {
        const vf4 top0 = b_tl0 + (b_tr0 - b_tl0) * s1.lx;
        const vf4 bot0 = b_bl0 + (b_br0 - b_bl0) * s1.lx;
        o10 = top0 + (bot0 - top0) * s1.ly;
        const vf4 top1 = b_tl1 + (b_tr1 - b_tl1) * s1.lx;
        const vf4 bot1 = b_bl1 + (b_br1 - b_bl1) * s1.lx;
        o11 = top1 + (bot1 - top1) * s1.ly;
    } else {
        o10 = (vf4)(0.0f); o11 = (vf4)(0.0f);
    }

    // NT stores won the R6 A/B (37.6 vs 39.0): keep them.
    vf4* op = ((vf4*)out) + (size_t)cell0 * C4 + c4;
    __builtin_nontemporal_store(o00, op);
    __builtin_nontemporal_store(o01, op + 64);
    __builtin_nontemporal_store(o10, op + 128);
    __builtin_nontemporal_store(o11, op + 192);
}

extern "C" void kernel_launch(void* const* d_in, const int* in_sizes, int n_in,
                              void* d_out, int out_size, void* d_ws, size_t ws_size,
                              hipStream_t stream)
{
    const float* fm  = (const float*)d_in[0];
    const float* nms = (const float*)d_in[1];
    float* out = (float*)d_out;

    roi_crop_resize_kernel<<<NBLOCKS, 256, 0, stream>>>(fm, nms, out);
}

// Round 8
// 38.056 us; speedup vs baseline: 1.0243x; 1.0004x over previous
//
#include <hip/hip_runtime.h>

// feature_map: (B=16, H=27, W=48, C=512) fp32
// nmses:       (B=16, R=100, 4) fp32  (cx, cy, w, h in pixels)
// output:      (B, R, 7, 7, C) fp32
#define BB   16
#define RR   100
#define HH   27
#define WW   48
#define CC   512
#define PP   7

#define C4       (CC / 4)            // 128 float4 per pixel
#define ROW4     (WW * C4)           // 6144 float4 per (b,y)
#define IMG4     (HH * ROW4)         // 165888 float4 per b

#define TOTAL4   (BB * RR * PP * PP * C4)   // 10,035,200 float4
#define NTHREADS (TOTAL4 / 4)               // 4 float4 per thread
#define NBLOCKS  (NTHREADS / 256)           // 9800; 9800 % 8 == 0
#define NXCD     8

typedef float vf4 __attribute__((ext_vector_type(4)));

// Per-cell sampling state (all wave-uniform / scalar).
struct CellS {
    const vf4* rT;
    const vf4* rB;
    int xo0, xo1;        // x0*C4, x1i*C4
    float lx, ly;
    bool valid;
};

__device__ __forceinline__ CellS cell_setup(const float* __restrict__ fm,
                                            const float* __restrict__ nms,
                                            int cell)
{
    CellS s;
    const int px = cell % PP;
    int t        = cell / PP;
    const int py = t % PP;
    t           /= PP;

    const int ts = __builtin_amdgcn_readfirstlane(t);
    const int b  = ts / RR;

    const vf4 box = ((const vf4*)nms)[ts];
    const float cx = box.x, cy = box.y, w = box.z, h = box.w;

    const float x1 = (cx - w * 0.5f) / 768.0f;
    const float x2 = (cx + w * 0.5f) / 768.0f;
    const float y1 = (cy - h * 0.5f) / 432.0f;
    const float y2 = (cy + h * 0.5f) / 432.0f;

    const float ys = y1 * 26.0f + (float)py * (y2 - y1) * 26.0f / 6.0f;
    const float xs = x1 * 47.0f + (float)px * (x2 - x1) * 47.0f / 6.0f;

    s.valid = (ys >= 0.0f) && (ys <= 26.0f) &&
              (xs >= 0.0f) && (xs <= 47.0f);

    const float y0f = floorf(ys);
    const float x0f = floorf(xs);
    s.ly = ys - y0f;
    s.lx = xs - x0f;

    int y0 = (int)y0f; y0 = min(max(y0, 0), HH - 1);
    const int y1i = min(y0 + 1, HH - 1);
    int x0 = (int)x0f; x0 = min(max(x0, 0), WW - 1);
    const int x1i = min(x0 + 1, WW - 1);

    const vf4* img = ((const vf4*)fm) + (size_t)b * IMG4;
    s.rT  = img + y0  * ROW4;
    s.rB  = img + y1i * ROW4;
    s.xo0 = x0  * C4;
    s.xo1 = x1i * C4;
    return s;
}

__global__ __launch_bounds__(256) void roi_crop_resize_kernel(
    const float* __restrict__ fm,
    const float* __restrict__ nms,
    float* __restrict__ out)
{
    // XCD-aware bijective swizzle (NBLOCKS % 8 == 0).
    const int bid  = blockIdx.x;
    const int wgid = (bid % NXCD) * (NBLOCKS / NXCD) + bid / NXCD;

    const int idx   = wgid * 256 + threadIdx.x;  // [0, NTHREADS)
    const int c4    = idx & 63;                  // lane's float4 slot
    const int pair  = idx >> 6;                  // wave handles 2 cells
    const int cell0 = pair * 2;
    const int cell1 = cell0 + 1;

    const CellS s0 = cell_setup(fm, nms, cell0);
    const CellS s1 = cell_setup(fm, nms, cell1);

    // Wave-uniform corner-sharing detection: cells are px-adjacent, so when
    // floor(xs) doesn't advance, cell1's corner addresses duplicate cell0's.
    // Eliminating the duplicate LOAD INSTRUCTIONS cuts VMEM-port bytes (an
    // L1 hit still costs full port occupancy; a register copy is free).
    const bool rows_same = s0.valid & s1.valid &
                           (s0.rT == s1.rT) & (s0.rB == s1.rB);
    const bool share_all = rows_same & (s1.xo0 == s0.xo0) & (s1.xo1 == s0.xo1);
    const bool share_col = rows_same & (!share_all) & (s1.xo0 == s0.xo1);

    vf4 a_tl0, a_tr0, a_bl0, a_br0, a_tl1, a_tr1, a_bl1, a_br1;
    vf4 b_tl0, b_tr0, b_bl0, b_br0, b_tl1, b_tr1, b_bl1, b_br1;

    if (s0.valid) {
        a_tl0 = s0.rT[s0.xo0 + c4];      a_tr0 = s0.rT[s0.xo1 + c4];
        a_bl0 = s0.rB[s0.xo0 + c4];      a_br0 = s0.rB[s0.xo1 + c4];
        a_tl1 = s0.rT[s0.xo0 + c4 + 64]; a_tr1 = s0.rT[s0.xo1 + c4 + 64];
        a_bl1 = s0.rB[s0.xo0 + c4 + 64]; a_br1 = s0.rB[s0.xo1 + c4 + 64];
    }
    if (s1.valid) {
        if (share_all) {
            // Identical 4 corner pixels: pure register reuse, 8 loads saved.
            b_tl0 = a_tl0; b_tr0 = a_tr0; b_bl0 = a_bl0; b_br0 = a_br0;
            b_tl1 = a_tl1; b_tr1 = a_tr1; b_bl1 = a_bl1; b_br1 = a_br1;
        } else if (share_col) {
            // cell1's left column == cell0's right column: 4 loads saved.
            b_tl0 = a_tr0; b_bl0 = a_br0;
            b_tl1 = a_tr1; b_bl1 = a_br1;
            b_tr0 = s1.rT[s1.xo1 + c4];      b_br0 = s1.rB[s1.xo1 + c4];
            b_tr1 = s1.rT[s1.xo1 + c4 + 64]; b_br1 = s1.rB[s1.xo1 + c4 + 64];
        } else {
            b_tl0 = s1.rT[s1.xo0 + c4];      b_tr0 = s1.rT[s1.xo1 + c4];
            b_bl0 = s1.rB[s1.xo0 + c4];      b_br0 = s1.rB[s1.xo1 + c4];
            b_tl1 = s1.rT[s1.xo0 + c4 + 64]; b_tr1 = s1.rT[s1.xo1 + c4 + 64];
            b_bl1 = s1.rB[s1.xo0 + c4 + 64]; b_br1 = s1.rB[s1.xo1 + c4 + 64];
        }
    }

    vf4 o00, o01, o10, o11;
    if (s0.valid) {
        const vf4 top0 = a_tl0 + (a_tr0 - a_tl0) * s0.lx;
        const vf4 bot0 = a_bl0 + (a_br0 - a_bl0) * s0.lx;
        o00 = top0 + (bot0 - top0) * s0.ly;
        const vf4 top1 = a_tl1 + (a_tr1 - a_tl1) * s0.lx;
        const vf4 bot1 = a_bl1 + (a_br1 - a_bl1) * s0.lx;
        o01 = top1 + (bot1 - top1) * s0.ly;
    } else {
        o00 = (vf4)(0.0f); o01 = (vf4)(0.0f);
    }
    if (s1.valid) {
        const vf4 top0 = b_tl0 + (b_tr0 - b_tl0) * s1.lx;
        const vf4 bot0 = b_bl0 + (b_br0 - b_bl0) * s1.lx;
        o10 = top0 + (bot0 - top0) * s1.ly;
        const vf4 top1 = b_tl1 + (b_tr1 - b_tl1) * s1.lx;
        const vf4 bot1 = b_bl1 + (b_br1 - b_bl1) * s1.lx;
        o11 = top1 + (bot1 - top1) * s1.ly;
    } else {
        o10 = (vf4)(0.0f); o11 = (vf4)(0.0f);
    }

    // NT stores won the R6 A/B (37.6 vs 39.0): keep them.
    vf4* op = ((vf4*)out) + (size_t)cell0 * C4 + c4;
    __builtin_nontemporal_store(o00, op);
    __builtin_nontemporal_store(o01, op + 64);
    __builtin_nontemporal_store(o10, op + 128);
    __builtin_nontemporal_store(o11, op + 192);
}

extern "C" void kernel_launch(void* const* d_in, const int* in_sizes, int n_in,
                              void* d_out, int out_size, void* d_ws, size_t ws_size,
                              hipStream_t stream)
{
    const float* fm  = (const float*)d_in[0];
    const float* nms = (const float*)d_in[1];
    float* out = (float*)d_out;

    roi_crop_resize_kernel<<<NBLOCKS, 256, 0, stream>>>(fm, nms, out);
}